// Round 1
// baseline (28.980 us; speedup 1.0000x reference)
//
#include <hip/hip_runtime.h>

#define FM_ROWS 16384
#define FM_NFEAT 50
#define FM_NDIM 17   // 16 embedding dims + 1 first-order column

__global__ __launch_bounds__(256) void FmLayer_14594298871894_kernel(
    const int* __restrict__ feat_index,   // [FM_ROWS][FM_NFEAT]
    const float* __restrict__ table,      // [1e6][FM_NDIM]
    float* __restrict__ out)              // [FM_ROWS][FM_NDIM]
{
    int gid = blockIdx.x * blockDim.x + threadIdx.x;
    const int total = FM_ROWS * FM_NDIM;
    if (gid >= total) return;

    int row = gid / FM_NDIM;          // compiler emits magic-mul
    int d   = gid - row * FM_NDIM;    // 0..16

    const int* idxp = feat_index + row * FM_NFEAT;

    float s = 0.0f;   // sum of x over features
    float q = 0.0f;   // sum of x^2 over features

    // 50 = 5 x 10: 10-deep unroll keeps 10 index loads + 10 gathers in flight.
    #pragma unroll
    for (int f0 = 0; f0 < FM_NFEAT; f0 += 10) {
        int idx[10];
        #pragma unroll
        for (int j = 0; j < 10; ++j) idx[j] = idxp[f0 + j];
        float x[10];
        #pragma unroll
        for (int j = 0; j < 10; ++j) x[j] = table[idx[j] * FM_NDIM + d];
        #pragma unroll
        for (int j = 0; j < 10; ++j) { s += x[j]; q = fmaf(x[j], x[j], q); }
    }

    if (d == 16) {
        out[row * FM_NDIM] = s;                          // first_order -> col 0
    } else {
        out[row * FM_NDIM + 1 + d] = 0.5f * (s * s - q); // second_order -> cols 1..16
    }
}

extern "C" void kernel_launch(void* const* d_in, const int* in_sizes, int n_in,
                              void* d_out, int out_size, void* d_ws, size_t ws_size,
                              hipStream_t stream) {
    const int*   feat_index = (const int*)d_in[0];   // 16384*50 int32
    const float* table      = (const float*)d_in[1]; // 1e6*17 float32
    float*       out        = (float*)d_out;         // 16384*17 float32

    const int total  = FM_ROWS * FM_NDIM;
    const int block  = 256;
    const int grid   = (total + block - 1) / block;
    FmLayer_14594298871894_kernel<<<grid, block, 0, stream>>>(feat_index, table, out);
}

// Round 2
// 28.064 us; speedup vs baseline: 1.0326x; 1.0326x over previous
//
#include <hip/hip_runtime.h>

#define FM_ROWS 16384
#define FM_NFEAT 50
#define FM_NDIM 17          // 16 embedding dims + 1 first-order column
#define ROWS_PER_BLOCK 15   // 15 rows x 17 dims = 255 active threads of 256
#define BLOCK 256

__global__ __launch_bounds__(BLOCK) void FmLayer_14594298871894_kernel(
    const int* __restrict__ feat_index,   // [FM_ROWS][FM_NFEAT]
    const float* __restrict__ table,      // [1e6][FM_NDIM]
    float* __restrict__ out)              // [FM_ROWS][FM_NDIM]
{
    __shared__ int sidx[ROWS_PER_BLOCK * FM_NFEAT];   // 750 ints = 3 KB

    const int tid  = threadIdx.x;
    const int row0 = blockIdx.x * ROWS_PER_BLOCK;
    const int nrows = min(ROWS_PER_BLOCK, FM_ROWS - row0);
    const int nidx  = nrows * FM_NFEAT;

    // Cooperative, coalesced stage of this block's indices into LDS.
    for (int i = tid; i < nidx; i += BLOCK)
        sidx[i] = feat_index[row0 * FM_NFEAT + i];
    __syncthreads();

    const int rl = tid / FM_NDIM;          // local row 0..14
    const int d  = tid - rl * FM_NDIM;     // dim 0..16
    if (rl >= nrows) return;

    const int* __restrict__ ip = sidx + rl * FM_NFEAT;

    float s = 0.0f;   // sum of x
    float q = 0.0f;   // sum of x^2

    // 50 = 2 x 25: 25 gathers in flight per thread (vmcnt allows 63).
    // Chain is now ds_read (~120cy) -> gather, instead of global idx load -> gather.
    #pragma unroll
    for (int f0 = 0; f0 < FM_NFEAT; f0 += 25) {
        float x[25];
        #pragma unroll
        for (int j = 0; j < 25; ++j) {
            // idx*17+d fits easily in 32-bit (max 17e6); saddr+voffset form.
            x[j] = table[ip[f0 + j] * FM_NDIM + d];
        }
        #pragma unroll
        for (int j = 0; j < 25; ++j) { s += x[j]; q = fmaf(x[j], x[j], q); }
    }

    if (d == 16) {
        out[row0 * FM_NDIM + rl * FM_NDIM] = s;                      // first_order -> col 0
    } else {
        out[(row0 + rl) * FM_NDIM + 1 + d] = 0.5f * (s * s - q);     // second_order -> cols 1..16
    }
}

extern "C" void kernel_launch(void* const* d_in, const int* in_sizes, int n_in,
                              void* d_out, int out_size, void* d_ws, size_t ws_size,
                              hipStream_t stream) {
    const int*   feat_index = (const int*)d_in[0];   // 16384*50 int32
    const float* table      = (const float*)d_in[1]; // 1e6*17 float32
    float*       out        = (float*)d_out;         // 16384*17 float32

    const int grid = (FM_ROWS + ROWS_PER_BLOCK - 1) / ROWS_PER_BLOCK;  // 1093
    FmLayer_14594298871894_kernel<<<grid, BLOCK, 0, stream>>>(feat_index, table, out);
}